// Round 1
// baseline (1436.030 us; speedup 1.0000x reference)
//
#include <hip/hip_runtime.h>

// ---------------------------------------------------------------------------
// Swin block on MI355X. Shapes (fixed): B=8, H=W=128, C=256, NH=8, HD=32,
// WS=8, SS=4, N=64 tok/window, NW=256 windows/img, tokens M=131072, HID=1024.
// ws layout (needs >= 256 MiB):
//   [0,192MiB)   qkv bf16 (131072x768)        -- later reused: y bf16 [0,64), h1 bf16 [64,192)
//   [192,256MiB) win bf16 (131072x256)        -- later reused: attn_out bf16
// x2 residual (f32) lives in d_out.
// ---------------------------------------------------------------------------

typedef __attribute__((ext_vector_type(4))) int            ivec4;
typedef __attribute__((ext_vector_type(4))) float          fvec4;
typedef __attribute__((ext_vector_type(8))) short          svec8;   // 8 bf16 = 4 VGPR
typedef __attribute__((ext_vector_type(8))) unsigned short usvec8;
typedef __attribute__((ext_vector_type(4))) float          floatx4;

#define SCALE_Q 0.17677669529663687f   // 32^-0.5

__device__ __forceinline__ unsigned short f2bf(float f) {
  union { float f; unsigned int u; } v; v.f = f;
  unsigned int r = v.u + 0x7FFFu + ((v.u >> 16) & 1u);   // RNE
  return (unsigned short)(r >> 16);
}

// ---------------------------------------------------------------------------
// LayerNorm (one token per block, 256 threads = 1 channel/thread).
// SHIFT=1: also apply cyclic shift (-4,-4) + window partition ordering:
//   token i = w*64+t maps to source pixel ((hr+4)&127, (wr+4)&127).
// ---------------------------------------------------------------------------
template<int SHIFT>
__global__ __launch_bounds__(256)
void ln_kernel(const float* __restrict__ x, const float* __restrict__ g,
               const float* __restrict__ b, unsigned short* __restrict__ out)
{
  const int i = blockIdx.x;
  const int c = threadIdx.x;
  size_t src;
  if constexpr (SHIFT) {
    int w  = i >> 6, t = i & 63;
    int bi = w >> 8, wi = w & 255;
    int hr = ((wi >> 4) << 3) + (t >> 3);
    int wr = ((wi & 15) << 3) + (t & 7);
    int ho = (hr + 4) & 127, wo = (wr + 4) & 127;
    src = ((size_t)bi * 16384 + (size_t)ho * 128 + wo) * 256 + c;
  } else {
    src = (size_t)i * 256 + c;
  }
  float v = x[src];
  float s = v, s2 = v * v;
  #pragma unroll
  for (int o = 32; o > 0; o >>= 1) { s += __shfl_xor(s, o); s2 += __shfl_xor(s2, o); }
  __shared__ float red[8];
  int wv = threadIdx.x >> 6;
  if ((threadIdx.x & 63) == 0) { red[wv] = s; red[4 + wv] = s2; }
  __syncthreads();
  float ts  = red[0] + red[1] + red[2] + red[3];
  float ts2 = red[4] + red[5] + red[6] + red[7];
  float mu  = ts * (1.0f / 256.0f);
  float var = ts2 * (1.0f / 256.0f) - mu * mu;
  float inv = rsqrtf(var + 1e-5f);
  out[(size_t)i * 256 + c] = f2bf((v - mu) * inv * g[c] + b[c]);
}

// ---------------------------------------------------------------------------
// GEMM: C[M,N] = A[M,K](bf16) * W[N,K](f32, converted to bf16 in staging)^T
// 128x128 tile, BK=32, 256 thr (4 waves), each wave 64x64 via 4x4 16x16x32 MFMA.
// LDS pitch 40 bf16 (80B, odd multiple of 16B -> conflict-free b128 frag reads).
// EPI: 0=qkv(+bias, scale q part), 1=proj(+bias,+window-reverse residual -> f32 out)
//      2=fc1(+bias, exact gelu -> bf16), 3=fc2(+bias,+x2 residual -> f32 out)
// ---------------------------------------------------------------------------
template<int EPI>
__global__ __launch_bounds__(256)
void gemm_bt(const unsigned short* __restrict__ A, const float* __restrict__ Wf,
             const float* __restrict__ bias,
             unsigned short* outb, float* outf, const float* extra,
             int N, int K, int row0)
{
  __shared__ unsigned short As[128 * 40];
  __shared__ unsigned short Bs[128 * 40];
  const int tid  = threadIdx.x;
  const int lane = tid & 63;
  const int wid  = tid >> 6;
  const int lo   = lane & 15, hi = lane >> 4;
  const int m0 = blockIdx.y * 128, n0 = blockIdx.x * 128;
  const int wm = (wid >> 1) * 64, wn = (wid & 1) * 64;

  floatx4 acc[4][4] = {};

  for (int kt = 0; kt < K; kt += 32) {
    #pragma unroll
    for (int it = 0; it < 2; ++it) {
      int idx = it * 256 + tid;
      int row = idx >> 2, ch = idx & 3;
      *(ivec4*)&As[row * 40 + ch * 8] =
          *(const ivec4*)(A + (size_t)(m0 + row) * K + kt + ch * 8);
      const float* pw = Wf + (size_t)(n0 + row) * K + kt + ch * 8;
      fvec4 w0 = *(const fvec4*)pw;
      fvec4 w1 = *(const fvec4*)(pw + 4);
      usvec8 tb;
      tb[0] = f2bf(w0.x); tb[1] = f2bf(w0.y); tb[2] = f2bf(w0.z); tb[3] = f2bf(w0.w);
      tb[4] = f2bf(w1.x); tb[5] = f2bf(w1.y); tb[6] = f2bf(w1.z); tb[7] = f2bf(w1.w);
      *(usvec8*)&Bs[row * 40 + ch * 8] = tb;
    }
    __syncthreads();
    svec8 af[4], bfr[4];
    #pragma unroll
    for (int i = 0; i < 4; ++i)
      af[i] = *(const svec8*)&As[(wm + i * 16 + lo) * 40 + hi * 8];
    #pragma unroll
    for (int i = 0; i < 4; ++i)
      bfr[i] = *(const svec8*)&Bs[(wn + i * 16 + lo) * 40 + hi * 8];
    #pragma unroll
    for (int mi = 0; mi < 4; ++mi)
      #pragma unroll
      for (int ni = 0; ni < 4; ++ni)
        acc[mi][ni] = __builtin_amdgcn_mfma_f32_16x16x32_bf16(af[mi], bfr[ni], acc[mi][ni], 0, 0, 0);
    __syncthreads();
  }

  #pragma unroll
  for (int mi = 0; mi < 4; ++mi) {
    #pragma unroll
    for (int ni = 0; ni < 4; ++ni) {
      #pragma unroll
      for (int j = 0; j < 4; ++j) {
        int r = m0 + wm + mi * 16 + hi * 4 + j;
        int c = n0 + wn + ni * 16 + lo;
        float v = acc[mi][ni][j] + bias[c];
        if constexpr (EPI == 0) {            // qkv: scale q part (cols < 256)
          if (c < 256) v *= SCALE_Q;
          outb[(size_t)r * N + c] = f2bf(v);
        } else if constexpr (EPI == 1) {     // proj + window-reverse + unshift + residual
          int w  = r >> 6, t = r & 63;
          int bi = w >> 8, wi = w & 255;
          int hr = ((wi >> 4) << 3) + (t >> 3);
          int wr = ((wi & 15) << 3) + (t & 7);
          int ho = (hr + 4) & 127, wo = (wr + 4) & 127;
          size_t o = ((size_t)bi * 16384 + (size_t)ho * 128 + wo) * 256 + c;
          outf[o] = extra[o] + v;
        } else if constexpr (EPI == 2) {     // fc1 + exact gelu
          float gv = 0.5f * v * (1.0f + erff(v * 0.70710678118654752f));
          outb[(size_t)r * N + c] = f2bf(gv);
        } else {                             // fc2 + residual (in place on d_out)
          size_t o = (size_t)(row0 + r) * N + c;
          outf[o] = extra[o] + v;
        }
      }
    }
  }
}

// ---------------------------------------------------------------------------
// Attention: one block per (window, head). 256 thr (4 waves).
// S = q@k^T (q pre-scaled in qkv epilogue), pe = depthwise conv_15 along query
// axis of S, + pe_b + rel-pos-bias + shift mask, softmax over keys, P@V.
// ---------------------------------------------------------------------------
__global__ __launch_bounds__(256)
void attn_kernel(const unsigned short* __restrict__ qkv,
                 const float* __restrict__ rpb_table,
                 const float* __restrict__ pe_w, const float* __restrict__ pe_b,
                 unsigned short* __restrict__ outb)
{
  __shared__ unsigned short qs[64 * 40];    // q (later: nothing)
  __shared__ unsigned short kls[64 * 40];   // k
  __shared__ unsigned short Vt[32 * 72];    // V transposed: Vt[d][kk]
  __shared__ float          Smat[64 * 65];  // logits f32
  __shared__ unsigned short Pm[64 * 72];    // softmaxed P bf16
  __shared__ float          rpbl[225];
  __shared__ float          wpe[15];
  __shared__ int            regid[64];

  const int tid  = threadIdx.x;
  const int wId  = blockIdx.x >> 3;   // window 0..2047
  const int h    = blockIdx.x & 7;    // head
  const int lane = tid & 63, wv = tid >> 6;
  const int lo   = lane & 15, hi = lane >> 4;

  { // stage q, k, V^T
    int r = tid >> 2, ch = tid & 3;
    const size_t base = (size_t)(wId * 64 + r) * 768 + h * 32 + ch * 8;
    *(ivec4*)&qs [r * 40 + ch * 8] = *(const ivec4*)(qkv + base);
    *(ivec4*)&kls[r * 40 + ch * 8] = *(const ivec4*)(qkv + base + 256);
    ivec4 vv = *(const ivec4*)(qkv + base + 512);
    const unsigned short* pv = (const unsigned short*)&vv;
    #pragma unroll
    for (int e = 0; e < 8; ++e) Vt[(ch * 8 + e) * 72 + r] = pv[e];
  }
  if (tid < 225) rpbl[tid] = rpb_table[tid * 8 + h];
  if (tid < 15)  wpe[tid]  = pe_w[h * 15 + tid];
  if (tid < 64) {
    int wi = wId & 255;
    int hh = ((wi >> 4) << 3) + (tid >> 3);
    int ww = ((wi & 15) << 3) + (tid & 7);
    int rh = (hh < 120) ? 0 : ((hh < 124) ? 1 : 2);
    int rw = (ww < 120) ? 0 : ((ww < 124) ? 1 : 2);
    regid[tid] = rh * 3 + rw;
  }
  __syncthreads();

  { // QK^T: wave wv owns rows [wv*16, wv*16+16)
    int m0 = wv * 16;
    svec8 a = *(const svec8*)&qs[(m0 + lo) * 40 + hi * 8];
    floatx4 accq[4] = {};
    #pragma unroll
    for (int nb = 0; nb < 4; ++nb) {
      svec8 bfr = *(const svec8*)&kls[(nb * 16 + lo) * 40 + hi * 8];
      accq[nb] = __builtin_amdgcn_mfma_f32_16x16x32_bf16(a, bfr, accq[nb], 0, 0, 0);
    }
    #pragma unroll
    for (int nb = 0; nb < 4; ++nb)
      #pragma unroll
      for (int j = 0; j < 4; ++j)
        Smat[(m0 + hi * 4 + j) * 65 + nb * 16 + lo] = accq[nb][j];
  }
  __syncthreads();

  // conv(15 along n) + pe_b + rpb + shift mask; thread t: col m=t&63, 16 rows
  float tv[16];
  {
    int mcol = tid & 63, nb0 = (tid >> 6) * 16;
    float pb = pe_b[h];
    int rm = regid[mcol];
    #pragma unroll
    for (int j = 0; j < 16; ++j) {
      int n = nb0 + j;
      float s = Smat[n * 65 + mcol];
      float pe = 0.0f;
      #pragma unroll
      for (int kk = 0; kk < 15; ++kk) {
        int nn = n + kk - 7;
        if (nn >= 0 && nn < 64) pe += wpe[kk] * Smat[nn * 65 + mcol];
      }
      int dy = (n >> 3) - (mcol >> 3) + 7;
      int dx = (n & 7) - (mcol & 7) + 7;
      s += pe + pb + rpbl[dy * 15 + dx];
      if (regid[n] != rm) s -= 100.0f;
      tv[j] = s;
    }
  }
  __syncthreads();
  {
    int mcol = tid & 63, nb0 = (tid >> 6) * 16;
    #pragma unroll
    for (int j = 0; j < 16; ++j) Smat[(nb0 + j) * 65 + mcol] = tv[j];
  }
  __syncthreads();

  { // softmax: row r = tid>>2, 4 threads/row, 16 cols each
    int r = tid >> 2, c0 = (tid & 3) * 16;
    float vals[16], mx = -1e30f;
    #pragma unroll
    for (int j = 0; j < 16; ++j) { vals[j] = Smat[r * 65 + c0 + j]; mx = fmaxf(mx, vals[j]); }
    mx = fmaxf(mx, __shfl_xor(mx, 1)); mx = fmaxf(mx, __shfl_xor(mx, 2));
    float sum = 0.0f;
    #pragma unroll
    for (int j = 0; j < 16; ++j) { vals[j] = __expf(vals[j] - mx); sum += vals[j]; }
    sum += __shfl_xor(sum, 1); sum += __shfl_xor(sum, 2);
    float inv = 1.0f / sum;
    usvec8 p0, p1;
    #pragma unroll
    for (int j = 0; j < 8; ++j) p0[j] = f2bf(vals[j] * inv);
    #pragma unroll
    for (int j = 0; j < 8; ++j) p1[j] = f2bf(vals[8 + j] * inv);
    *(usvec8*)&Pm[r * 72 + c0]     = p0;
    *(usvec8*)&Pm[r * 72 + c0 + 8] = p1;
  }
  __syncthreads();

  { // PV: wave wv rows [wv*16,+16), out cols 0..31
    int m0 = wv * 16;
    floatx4 acco[2] = {};
    #pragma unroll
    for (int ks = 0; ks < 2; ++ks) {
      svec8 pa = *(const svec8*)&Pm[(m0 + lo) * 72 + ks * 32 + hi * 8];
      #pragma unroll
      for (int nb = 0; nb < 2; ++nb) {
        svec8 vb = *(const svec8*)&Vt[(nb * 16 + lo) * 72 + ks * 32 + hi * 8];
        acco[nb] = __builtin_amdgcn_mfma_f32_16x16x32_bf16(pa, vb, acco[nb], 0, 0, 0);
      }
    }
    #pragma unroll
    for (int nb = 0; nb < 2; ++nb)
      #pragma unroll
      for (int j = 0; j < 4; ++j) {
        int r = m0 + hi * 4 + j, c = nb * 16 + lo;
        outb[(size_t)(wId * 64 + r) * 256 + h * 32 + c] = f2bf(acco[nb][j]);
      }
  }
}

// ---------------------------------------------------------------------------
extern "C" void kernel_launch(void* const* d_in, const int* in_sizes, int n_in,
                              void* d_out, int out_size, void* d_ws, size_t ws_size,
                              hipStream_t stream)
{
  const float* x      = (const float*)d_in[0];
  const float* n1g    = (const float*)d_in[1];
  const float* n1b    = (const float*)d_in[2];
  const float* qkv_w  = (const float*)d_in[3];
  const float* qkv_b  = (const float*)d_in[4];
  const float* rpb    = (const float*)d_in[5];
  const float* pe_w   = (const float*)d_in[6];
  const float* pe_b   = (const float*)d_in[7];
  const float* proj_w = (const float*)d_in[8];
  const float* proj_b = (const float*)d_in[9];
  const float* n2g    = (const float*)d_in[10];
  const float* n2b    = (const float*)d_in[11];
  const float* fc1_w  = (const float*)d_in[12];
  const float* fc1_b  = (const float*)d_in[13];
  const float* fc2_w  = (const float*)d_in[14];
  const float* fc2_b  = (const float*)d_in[15];
  float* outf = (float*)d_out;

  unsigned short* qkvb = (unsigned short*)d_ws;                          // 192 MiB
  unsigned short* winb = (unsigned short*)((char*)d_ws + (192ull << 20)); // 64 MiB (win, then attn_out)
  unsigned short* yb   = (unsigned short*)d_ws;                           // 64 MiB (reuse qkv)
  unsigned short* h1b  = (unsigned short*)((char*)d_ws + (64ull << 20));  // 128 MiB (reuse qkv)

  // 1) LN1 + shift + window partition -> win bf16
  ln_kernel<1><<<131072, 256, 0, stream>>>(x, n1g, n1b, winb);
  // 2) QKV GEMM (q pre-scaled) -> qkv bf16
  gemm_bt<0><<<dim3(6, 1024), 256, 0, stream>>>(winb, qkv_w, qkv_b, qkvb, nullptr, nullptr, 768, 256, 0);
  // 3) windowed attention -> attn_out bf16 (overwrites win)
  attn_kernel<<<16384, 256, 0, stream>>>(qkvb, rpb, pe_w, pe_b, winb);
  // 4) proj GEMM + window reverse + unshift + residual -> x2 (f32, in d_out)
  gemm_bt<1><<<dim3(2, 1024), 256, 0, stream>>>(winb, proj_w, proj_b, nullptr, outf, x, 256, 256, 0);
  // 5) LN2 -> y bf16 (reuses qkv region)
  ln_kernel<0><<<131072, 256, 0, stream>>>(outf, n2g, n2b, yb);
  // 6) MLP in two M-halves so h1 fits in 128 MiB
  for (int half = 0; half < 2; ++half) {
    int r0 = half * 65536;
    gemm_bt<2><<<dim3(8, 512), 256, 0, stream>>>(yb + (size_t)r0 * 256, fc1_w, fc1_b, h1b, nullptr, nullptr, 1024, 256, 0);
    gemm_bt<3><<<dim3(2, 512), 256, 0, stream>>>(h1b, fc2_w, fc2_b, nullptr, outf, outf, 256, 1024, r0);
  }
}

// Round 2
// 1103.688 us; speedup vs baseline: 1.3011x; 1.3011x over previous
//
#include <hip/hip_runtime.h>

// ---------------------------------------------------------------------------
// Swin block on MI355X. B=8, H=W=128, C=256, NH=8, HD=32, WS=8, SS=4, N=64,
// NW=256, tokens M=131072, HID=1024.
// ws (256 MiB): [0,192M) qkv bf16 | [192,256M) win/attn_out bf16
//   after attn, [0,192M) is reused: y [0,64M), h1 [64,128M), w_bf16 [128M,+1.25M)
// d_out doubles as scratch before proj: qkv_wb [0,384K), rpbm [512K,1M), mconv [1M,+64K)
// ---------------------------------------------------------------------------

typedef unsigned short u16;
typedef unsigned int   u32;
typedef __attribute__((ext_vector_type(4))) int   ivec4;
typedef __attribute__((ext_vector_type(4))) float fvec4;
typedef __attribute__((ext_vector_type(8))) short svec8;
typedef __attribute__((ext_vector_type(4))) unsigned short usvec4;
typedef __attribute__((ext_vector_type(4))) float floatx4;

#define SCALE_Q 0.17677669529663687f

__device__ __forceinline__ u16 f2bf(float f) {
  union { float f; u32 u; } v; v.f = f;
  u32 r = v.u + 0x7FFFu + ((v.u >> 16) & 1u);
  return (u16)(r >> 16);
}

__device__ __forceinline__ void async_copy16(const u16* g, u16* l) {
  __builtin_amdgcn_global_load_lds(
      (const __attribute__((address_space(1))) u32*)g,
      (__attribute__((address_space(3))) u32*)l, 16, 0, 0);
}

// ---------------------------------------------------------------------------
// LayerNorm. SHIFT=1: + cyclic shift(-4,-4) + window partition.
// ---------------------------------------------------------------------------
template<int SHIFT>
__global__ __launch_bounds__(256)
void ln_kernel(const float* __restrict__ x, const float* __restrict__ g,
               const float* __restrict__ b, u16* __restrict__ out)
{
  const int i = blockIdx.x;
  const int c = threadIdx.x;
  size_t src;
  if constexpr (SHIFT) {
    int w  = i >> 6, t = i & 63;
    int bi = w >> 8, wi = w & 255;
    int hr = ((wi >> 4) << 3) + (t >> 3);
    int wr = ((wi & 15) << 3) + (t & 7);
    int ho = (hr + 4) & 127, wo = (wr + 4) & 127;
    src = ((size_t)bi * 16384 + (size_t)ho * 128 + wo) * 256 + c;
  } else {
    src = (size_t)i * 256 + c;
  }
  float v = x[src];
  float s = v, s2 = v * v;
  #pragma unroll
  for (int o = 32; o > 0; o >>= 1) { s += __shfl_xor(s, o); s2 += __shfl_xor(s2, o); }
  __shared__ float red[8];
  int wv = threadIdx.x >> 6;
  if ((threadIdx.x & 63) == 0) { red[wv] = s; red[4 + wv] = s2; }
  __syncthreads();
  float ts  = red[0] + red[1] + red[2] + red[3];
  float ts2 = red[4] + red[5] + red[6] + red[7];
  float mu  = ts * (1.0f / 256.0f);
  float var = ts2 * (1.0f / 256.0f) - mu * mu;
  float inv = rsqrtf(var + 1e-5f);
  out[(size_t)i * 256 + c] = f2bf((v - mu) * inv * g[c] + b[c]);
}

// ---------------------------------------------------------------------------
// Small setup kernels
// ---------------------------------------------------------------------------
__global__ __launch_bounds__(256)
void cvt_kernel(const float* __restrict__ src, u16* __restrict__ dst, int n) {
  int i = (blockIdx.x * 256 + threadIdx.x) * 4;
  if (i < n) {
    fvec4 v = *(const fvec4*)(src + i);
    usvec4 o; o[0] = f2bf(v.x); o[1] = f2bf(v.y); o[2] = f2bf(v.z); o[3] = f2bf(v.w);
    *(usvec4*)(dst + i) = o;
  }
}

// rpbm[cls][h][n][m] = rpb[relidx(n,m)][h] + pe_b[h] + mask(cls,n,m)
__global__ __launch_bounds__(256)
void rpbm_kernel(const float* __restrict__ rpb, const float* __restrict__ pe_b,
                 float* __restrict__ out) {
  int idx = blockIdx.x * 256 + threadIdx.x;          // 131072
  int m = idx & 63, n = (idx >> 6) & 63, hh = (idx >> 12) & 7, cls = idx >> 15;
  int dy = (n >> 3) - (m >> 3) + 7, dx = (n & 7) - (m & 7) + 7;
  float v = rpb[(dy * 15 + dx) * 8 + hh] + pe_b[hh];
  int lastR = cls >> 1, lastC = cls & 1;
  int rn = lastR ? (((n >> 3) < 4) ? 1 : 2) : 0;
  int cn = lastC ? (((n & 7) < 4) ? 1 : 2) : 0;
  int rm = lastR ? (((m >> 3) < 4) ? 1 : 2) : 0;
  int cm = lastC ? (((m & 7) < 4) ? 1 : 2) : 0;
  if (rn * 3 + cn != rm * 3 + cm) v -= 100.0f;
  out[idx] = v;
}

// mconv[h][n][nn] = (n==nn) + (|nn-n|<=7 ? pe_w[h][nn-n+7] : 0), bf16
__global__ __launch_bounds__(256)
void mconv_kernel(const float* __restrict__ pe_w, u16* __restrict__ out) {
  int idx = blockIdx.x * 256 + threadIdx.x;          // 32768
  int nn = idx & 63, n = (idx >> 6) & 63, hh = idx >> 12;
  int d = nn - n;
  float v = (d == 0) ? 1.0f : 0.0f;
  if (d >= -7 && d <= 7) v += pe_w[hh * 15 + d + 7];
  out[idx] = f2bf(v);
}

// ---------------------------------------------------------------------------
// m97-style GEMM: C[M,N] = A[M,K]bf16 * B[N,K]bf16^T. 128x128 tile, BK=32,
// global_load_lds width16 staging, linear LDS, 2-barrier K-loop.
// EPI: 0 qkv (+bias, scale q) | 1 proj (+bias + window-reverse residual -> f32)
//      2 fc1 (+bias, exact gelu) | 3 fc2 (+bias + residual in d_out)
// ---------------------------------------------------------------------------
template<int EPI>
__global__ __launch_bounds__(256)
void gemm2(const u16* __restrict__ A, const u16* __restrict__ Bw,
           const float* __restrict__ bias, u16* outb, float* outf,
           const float* __restrict__ extra, int N, int K, int row0)
{
  __shared__ __align__(16) u16 As[128 * 32];
  __shared__ __align__(16) u16 Bs[128 * 32];
  const int tid  = threadIdx.x;
  const int lane = tid & 63;
  const int wid  = tid >> 6;
  const int lo   = lane & 15, hi = lane >> 4;
  const int m0 = blockIdx.y * 128, n0 = blockIdx.x * 128;
  const int wm = (wid >> 1) * 64, wn = (wid & 1) * 64;

  floatx4 acc[4][4] = {};

  const int r0c = tid >> 2, q0 = tid & 3;            // part 0 chunk
  const int r1c = (256 + tid) >> 2, q1 = tid & 3;    // part 1 chunk

  auto issue = [&](int kt) {
    async_copy16(A + (size_t)(m0 + r0c) * K + kt + q0 * 8, &As[(size_t)tid * 8]);
    async_copy16(A + (size_t)(m0 + r1c) * K + kt + q1 * 8, &As[(size_t)(256 + tid) * 8]);
    async_copy16(Bw + (size_t)(n0 + r0c) * K + kt + q0 * 8, &Bs[(size_t)tid * 8]);
    async_copy16(Bw + (size_t)(n0 + r1c) * K + kt + q1 * 8, &Bs[(size_t)(256 + tid) * 8]);
  };

  issue(0);
  int kt = 0;
  while (true) {
    __syncthreads();                      // staged tile landed (vmcnt drained)
    svec8 af[4], bfr[4];
    #pragma unroll
    for (int i = 0; i < 4; ++i)
      af[i] = *(const svec8*)&As[(wm + i * 16 + lo) * 32 + hi * 8];
    #pragma unroll
    for (int i = 0; i < 4; ++i)
      bfr[i] = *(const svec8*)&Bs[(wn + i * 16 + lo) * 32 + hi * 8];
    __syncthreads();                      // all reads done -> safe to overwrite
    kt += 32;
    if (kt < K) issue(kt);
    #pragma unroll
    for (int mi = 0; mi < 4; ++mi)
      #pragma unroll
      for (int ni = 0; ni < 4; ++ni)
        acc[mi][ni] = __builtin_amdgcn_mfma_f32_16x16x32_bf16(af[mi], bfr[ni], acc[mi][ni], 0, 0, 0);
    if (kt >= K) break;
  }

  #pragma unroll
  for (int mi = 0; mi < 4; ++mi) {
    #pragma unroll
    for (int ni = 0; ni < 4; ++ni) {
      #pragma unroll
      for (int j = 0; j < 4; ++j) {
        int r = m0 + wm + mi * 16 + hi * 4 + j;
        int c = n0 + wn + ni * 16 + lo;
        float v = acc[mi][ni][j] + bias[c];
        if constexpr (EPI == 0) {
          if (c < 256) v *= SCALE_Q;
          outb[(size_t)r * N + c] = f2bf(v);
        } else if constexpr (EPI == 1) {
          int w  = r >> 6, t = r & 63;
          int bi = w >> 8, wi = w & 255;
          int hr = ((wi >> 4) << 3) + (t >> 3);
          int wr = ((wi & 15) << 3) + (t & 7);
          int ho = (hr + 4) & 127, wo = (wr + 4) & 127;
          size_t o = ((size_t)bi * 16384 + (size_t)ho * 128 + wo) * 256 + c;
          outf[o] = extra[o] + v;
        } else if constexpr (EPI == 2) {
          float gv = 0.5f * v * (1.0f + erff(v * 0.70710678118654752f));
          outb[(size_t)r * N + c] = f2bf(gv);
        } else {
          size_t o = (size_t)(row0 + r) * N + c;
          outf[o] = extra[o] + v;
        }
      }
    }
  }
}

// ---------------------------------------------------------------------------
// Attention v2: one block per (window, head), 4 waves; wave wv owns queries
// [wv*16, wv*16+16). QK^T from global frags (q) + LDS-staged k. Logits =
// (I+T) @ S_bf16 (MFMA, acc init = rpbm). In-register softmax. PV via LDS.
// ---------------------------------------------------------------------------
__global__ __launch_bounds__(256)
void attn2(const u16* __restrict__ qkv, const float* __restrict__ rpbm,
           const u16* __restrict__ mconv, u16* __restrict__ outb)
{
  __shared__ __align__(16) u16 Ks[64 * 40];   // k  [token][32]  pitch 40
  __shared__ __align__(16) u16 Vt[32 * 72];   // V^T [d][token]  pitch 72
  __shared__ __align__(16) u16 ST[64 * 72];   // S^T [key][query] pitch 72
  __shared__ __align__(16) u16 Pm[64 * 72];   // P  [query][key] pitch 72

  const int tid  = threadIdx.x;
  const int lane = tid & 63, wv = tid >> 6;
  const int lo   = lane & 15, hi = lane >> 4;
  const int wId  = blockIdx.x >> 3;
  const int h    = blockIdx.x & 7;
  const int wi   = wId & 255;
  const int cls  = (((wi >> 4) == 15) ? 2 : 0) + (((wi & 15) == 15) ? 1 : 0);
  const int m0   = wv * 16;

  { // stage k and V^T
    int r = tid >> 2, ch = tid & 3;
    const size_t base = (size_t)(wId * 64 + r) * 768 + h * 32 + ch * 8;
    *(ivec4*)&Ks[r * 40 + ch * 8] = *(const ivec4*)(qkv + base + 256);
    ivec4 vv = *(const ivec4*)(qkv + base + 512);
    const u16* pv = (const u16*)&vv;
    #pragma unroll
    for (int e = 0; e < 8; ++e) Vt[(ch * 8 + e) * 72 + r] = pv[e];
  }
  __syncthreads();

  { // QK^T (K=32): A = q rows (global), B = k rows (LDS). Write S^T bf16.
    svec8 qa = *(const svec8*)(qkv + (size_t)(wId * 64 + m0 + lo) * 768 + h * 32 + hi * 8);
    floatx4 z = {0.f, 0.f, 0.f, 0.f};
    #pragma unroll
    for (int nb = 0; nb < 4; ++nb) {
      svec8 kb = *(const svec8*)&Ks[(nb * 16 + lo) * 40 + hi * 8];
      floatx4 s = __builtin_amdgcn_mfma_f32_16x16x32_bf16(qa, kb, z, 0, 0, 0);
      #pragma unroll
      for (int jp = 0; jp < 2; ++jp) {
        u32 pk = (u32)f2bf(s[jp * 2]) | ((u32)f2bf(s[jp * 2 + 1]) << 16);
        *(u32*)&ST[(nb * 16 + lo) * 72 + m0 + hi * 4 + jp * 2] = pk;
      }
    }
  }
  __syncthreads();

  // conv-MFMA: L = (I+T) @ S, acc init = rpbm (+pe_b +mask folded in)
  floatx4 acc[4];
  {
    const float* rb = rpbm + (size_t)(cls * 8 + h) * 4096;
    #pragma unroll
    for (int nb = 0; nb < 4; ++nb)
      #pragma unroll
      for (int j = 0; j < 4; ++j)
        acc[nb][j] = rb[(m0 + hi * 4 + j) * 64 + nb * 16 + lo];
    svec8 mf0 = *(const svec8*)(mconv + ((h * 64 + m0 + lo) * 64 + hi * 8));
    svec8 mf1 = *(const svec8*)(mconv + ((h * 64 + m0 + lo) * 64 + 32 + hi * 8));
    #pragma unroll
    for (int nb = 0; nb < 4; ++nb) {
      svec8 st0 = *(const svec8*)&ST[(nb * 16 + lo) * 72 + hi * 8];
      svec8 st1 = *(const svec8*)&ST[(nb * 16 + lo) * 72 + 32 + hi * 8];
      acc[nb] = __builtin_amdgcn_mfma_f32_16x16x32_bf16(mf0, st0, acc[nb], 0, 0, 0);
      acc[nb] = __builtin_amdgcn_mfma_f32_16x16x32_bf16(mf1, st1, acc[nb], 0, 0, 0);
    }
  }

  { // in-register softmax over keys (4 nb regs x 16 lo lanes)
    float ev[4][4], inv[4];
    #pragma unroll
    for (int j = 0; j < 4; ++j) {
      float m_ = fmaxf(fmaxf(acc[0][j], acc[1][j]), fmaxf(acc[2][j], acc[3][j]));
      m_ = fmaxf(m_, __shfl_xor(m_, 1)); m_ = fmaxf(m_, __shfl_xor(m_, 2));
      m_ = fmaxf(m_, __shfl_xor(m_, 4)); m_ = fmaxf(m_, __shfl_xor(m_, 8));
      #pragma unroll
      for (int nb = 0; nb < 4; ++nb) ev[nb][j] = __expf(acc[nb][j] - m_);
      float s_ = ev[0][j] + ev[1][j] + ev[2][j] + ev[3][j];
      s_ += __shfl_xor(s_, 1); s_ += __shfl_xor(s_, 2);
      s_ += __shfl_xor(s_, 4); s_ += __shfl_xor(s_, 8);
      inv[j] = __builtin_amdgcn_rcpf(s_);
    }
    #pragma unroll
    for (int nb = 0; nb < 4; ++nb)
      #pragma unroll
      for (int j = 0; j < 4; ++j)
        Pm[(m0 + hi * 4 + j) * 72 + nb * 16 + lo] = f2bf(ev[nb][j] * inv[j]);
  }
  __syncthreads();

  { // PV: A = P rows (queries), B = V^T rows (d). K = 64 keys.
    floatx4 oacc[2] = {};
    #pragma unroll
    for (int ks = 0; ks < 2; ++ks) {
      svec8 pa = *(const svec8*)&Pm[(m0 + lo) * 72 + ks * 32 + hi * 8];
      #pragma unroll
      for (int nb = 0; nb < 2; ++nb) {
        svec8 vb = *(const svec8*)&Vt[(nb * 16 + lo) * 72 + ks * 32 + hi * 8];
        oacc[nb] = __builtin_amdgcn_mfma_f32_16x16x32_bf16(pa, vb, oacc[nb], 0, 0, 0);
      }
    }
    #pragma unroll
    for (int nb = 0; nb < 2; ++nb)
      #pragma unroll
      for (int j = 0; j < 4; ++j)
        outb[(size_t)(wId * 64 + m0 + hi * 4 + j) * 256 + h * 32 + nb * 16 + lo] = f2bf(oacc[nb][j]);
  }
}

// ---------------------------------------------------------------------------
extern "C" void kernel_launch(void* const* d_in, const int* in_sizes, int n_in,
                              void* d_out, int out_size, void* d_ws, size_t ws_size,
                              hipStream_t stream)
{
  const float* x      = (const float*)d_in[0];
  const float* n1g    = (const float*)d_in[1];
  const float* n1b    = (const float*)d_in[2];
  const float* qkv_w  = (const float*)d_in[3];
  const float* qkv_b  = (const float*)d_in[4];
  const float* rpb    = (const float*)d_in[5];
  const float* pe_w   = (const float*)d_in[6];
  const float* pe_b   = (const float*)d_in[7];
  const float* proj_w = (const float*)d_in[8];
  const float* proj_b = (const float*)d_in[9];
  const float* n2g    = (const float*)d_in[10];
  const float* n2b    = (const float*)d_in[11];
  const float* fc1_w  = (const float*)d_in[12];
  const float* fc1_b  = (const float*)d_in[13];
  const float* fc2_w  = (const float*)d_in[14];
  const float* fc2_b  = (const float*)d_in[15];
  float* outf = (float*)d_out;

  char* ws = (char*)d_ws;
  u16* qkvb   = (u16*)ws;                                  // [0,192M)
  u16* winb   = (u16*)(ws + (192ull << 20));               // [192,256M)
  u16* yb     = (u16*)ws;                                  // [0,64M)   (post-attn)
  u16* h1b    = (u16*)(ws + (64ull << 20));                // [64,128M) (post-attn)
  u16* projwb = (u16*)(ws + (128ull << 20));               // 128K
  u16* fc1wb  = (u16*)(ws + (128ull << 20) + (1ull << 18));// 512K
  u16* fc2wb  = (u16*)(ws + (128ull << 20) + (1ull << 18) + (1ull << 19));

  u16*   qkvwb  = (u16*)d_out;                             // 384K (pre-proj scratch)
  float* rpbmT  = (float*)((char*)d_out + (1ull << 19));   // 512K
  u16*   mconvT = (u16*)((char*)d_out + (1ull << 20));     // 64K

  // setup: weight converts + tables (d_out scratch, dead until proj)
  cvt_kernel<<<192, 256, 0, stream>>>(qkv_w, qkvwb, 196608);
  rpbm_kernel<<<512, 256, 0, stream>>>(rpb, pe_b, rpbmT);
  mconv_kernel<<<128, 256, 0, stream>>>(pe_w, mconvT);

  // 1) LN1 + shift + window partition
  ln_kernel<1><<<131072, 256, 0, stream>>>(x, n1g, n1b, winb);
  // 2) QKV GEMM
  gemm2<0><<<dim3(6, 1024), 256, 0, stream>>>(winb, qkvwb, qkv_b, qkvb, nullptr, nullptr, 768, 256, 0);
  // 3) attention
  attn2<<<16384, 256, 0, stream>>>(qkvb, rpbmT, mconvT, winb);
  // 3b) convert proj/fc weights into dead qkv region
  cvt_kernel<<<64, 256, 0, stream>>>(proj_w, projwb, 65536);
  cvt_kernel<<<256, 256, 0, stream>>>(fc1_w, fc1wb, 262144);
  cvt_kernel<<<256, 256, 0, stream>>>(fc2_w, fc2wb, 262144);
  // 4) proj + window-reverse + unshift + residual -> d_out f32
  gemm2<1><<<dim3(2, 1024), 256, 0, stream>>>(winb, projwb, proj_b, nullptr, outf, x, 256, 256, 0);
  // 5) LN2
  ln_kernel<0><<<131072, 256, 0, stream>>>(outf, n2g, n2b, yb);
  // 6) MLP in four M-quarters (h1 fits in 64M)
  for (int qtr = 0; qtr < 4; ++qtr) {
    int r0 = qtr * 32768;
    gemm2<2><<<dim3(8, 256), 256, 0, stream>>>(yb + (size_t)r0 * 256, fc1wb, fc1_b, h1b, nullptr, nullptr, 1024, 256, 0);
    gemm2<3><<<dim3(2, 256), 256, 0, stream>>>(h1b, fc2wb, fc2_b, nullptr, outf, outf, 256, 1024, r0);
  }
}

// Round 3
// 945.580 us; speedup vs baseline: 1.5187x; 1.1672x over previous
//
#include <hip/hip_runtime.h>

// ---------------------------------------------------------------------------
// Swin block on MI355X. B=8, H=W=128, C=256, NH=8, HD=32, WS=8, SS=4, N=64,
// NW=256, tokens M=131072, HID=1024.
// ws (256 MiB):
//   phase1: qkvb [0,192M) | winb [192,256M)
//   phase2 (post-attn): yb [0,64M) | h1b [64,192M) | projout [128,192M) (dead
//           before h1b written) | fc1wb/fc2wb [192,256M) (after proj reads winb)
// d_out doubles as scratch until resid_ln2: qkvwb [0,384K), rpbm [512K,1M),
//   mconv [1M,1M+64K), projwb [1.25M,+128K)
// ---------------------------------------------------------------------------

typedef unsigned short u16;
typedef unsigned int   u32;
typedef __attribute__((ext_vector_type(4))) int   ivec4;
typedef __attribute__((ext_vector_type(4))) float fvec4;
typedef __attribute__((ext_vector_type(8))) short svec8;
typedef __attribute__((ext_vector_type(4))) unsigned short usvec4;
typedef __attribute__((ext_vector_type(4))) float floatx4;

#define SCALE_Q 0.17677669529663687f

__device__ __forceinline__ u16 f2bf(float f) {
  union { float f; u32 u; } v; v.f = f;
  u32 r = v.u + 0x7FFFu + ((v.u >> 16) & 1u);
  return (u16)(r >> 16);
}
__device__ __forceinline__ float bf2f(u16 h) {
  union { u32 u; float f; } v; v.u = ((u32)h) << 16; return v.f;
}

__device__ __forceinline__ void async_copy16(const u16* g, u16* l) {
  __builtin_amdgcn_global_load_lds(
      (const __attribute__((address_space(1))) u32*)g,
      (__attribute__((address_space(3))) u32*)l, 16, 0, 0);
}

// ---------------------------------------------------------------------------
// LN1: wave per token (4 tokens/block), float4/lane, shuffle-only reduce.
// SHIFT=1: token order = shifted window partition (gather read of x).
// ---------------------------------------------------------------------------
template<int SHIFT>
__global__ __launch_bounds__(256)
void ln_kernel(const float* __restrict__ x, const float* __restrict__ g,
               const float* __restrict__ b, u16* __restrict__ out)
{
  const int t    = blockIdx.x * 4 + (threadIdx.x >> 6);
  const int lane = threadIdx.x & 63;
  const int c    = lane * 4;
  size_t src;
  if constexpr (SHIFT) {
    int w  = t >> 6, tk = t & 63;
    int bi = w >> 8, wi = w & 255;
    int hr = ((wi >> 4) << 3) + (tk >> 3);
    int wr = ((wi & 15) << 3) + (tk & 7);
    int ho = (hr + 4) & 127, wo = (wr + 4) & 127;
    src = ((size_t)bi * 16384 + (size_t)ho * 128 + wo) * 256 + c;
  } else {
    src = (size_t)t * 256 + c;
  }
  fvec4 v = *(const fvec4*)(x + src);
  float s  = v.x + v.y + v.z + v.w;
  float s2 = v.x * v.x + v.y * v.y + v.z * v.z + v.w * v.w;
  #pragma unroll
  for (int o = 32; o > 0; o >>= 1) { s += __shfl_xor(s, o); s2 += __shfl_xor(s2, o); }
  float mu  = s * (1.0f / 256.0f);
  float var = s2 * (1.0f / 256.0f) - mu * mu;
  float inv = rsqrtf(var + 1e-5f);
  fvec4 gg = *(const fvec4*)(g + c);
  fvec4 bb = *(const fvec4*)(b + c);
  usvec4 o4;
  o4[0] = f2bf((v.x - mu) * inv * gg.x + bb.x);
  o4[1] = f2bf((v.y - mu) * inv * gg.y + bb.y);
  o4[2] = f2bf((v.z - mu) * inv * gg.z + bb.z);
  o4[3] = f2bf((v.w - mu) * inv * gg.w + bb.w);
  *(usvec4*)(out + (size_t)t * 256 + c) = o4;
}

// ---------------------------------------------------------------------------
// resid_ln2: wave per pixel P (row-major). x2 = x + permute(proj_out);
// write x2 (f32, d_out) and LN2(x2) (bf16, yb). Gather is >=512B-granular.
// ---------------------------------------------------------------------------
__global__ __launch_bounds__(256)
void resid_ln2(const float* __restrict__ x, const u16* __restrict__ projout,
               const float* __restrict__ g, const float* __restrict__ b,
               float* __restrict__ x2, u16* __restrict__ yb)
{
  const int P    = blockIdx.x * 4 + (threadIdx.x >> 6);
  const int lane = threadIdx.x & 63;
  const int c    = lane * 4;
  const int bi = P >> 14, ho = (P >> 7) & 127, wo = P & 127;
  const int hr = (ho + 124) & 127, wr = (wo + 124) & 127;
  const int token = (((bi << 8) + ((hr >> 3) << 4) + (wr >> 3)) << 6)
                    + ((hr & 7) << 3) + (wr & 7);
  fvec4 xv = *(const fvec4*)(x + (size_t)P * 256 + c);
  usvec4 pv = *(const usvec4*)(projout + (size_t)token * 256 + c);
  fvec4 v;
  v.x = xv.x + bf2f(pv[0]); v.y = xv.y + bf2f(pv[1]);
  v.z = xv.z + bf2f(pv[2]); v.w = xv.w + bf2f(pv[3]);
  *(fvec4*)(x2 + (size_t)P * 256 + c) = v;
  float s  = v.x + v.y + v.z + v.w;
  float s2 = v.x * v.x + v.y * v.y + v.z * v.z + v.w * v.w;
  #pragma unroll
  for (int o = 32; o > 0; o >>= 1) { s += __shfl_xor(s, o); s2 += __shfl_xor(s2, o); }
  float mu  = s * (1.0f / 256.0f);
  float var = s2 * (1.0f / 256.0f) - mu * mu;
  float inv = rsqrtf(var + 1e-5f);
  fvec4 gg = *(const fvec4*)(g + c);
  fvec4 bb = *(const fvec4*)(b + c);
  usvec4 o4;
  o4[0] = f2bf((v.x - mu) * inv * gg.x + bb.x);
  o4[1] = f2bf((v.y - mu) * inv * gg.y + bb.y);
  o4[2] = f2bf((v.z - mu) * inv * gg.z + bb.z);
  o4[3] = f2bf((v.w - mu) * inv * gg.w + bb.w);
  *(usvec4*)(yb + (size_t)P * 256 + c) = o4;
}

// ---------------------------------------------------------------------------
// Small setup kernels
// ---------------------------------------------------------------------------
__global__ __launch_bounds__(256)
void cvt_kernel(const float* __restrict__ src, u16* __restrict__ dst, int n) {
  int i = (blockIdx.x * 256 + threadIdx.x) * 4;
  if (i < n) {
    fvec4 v = *(const fvec4*)(src + i);
    usvec4 o; o[0] = f2bf(v.x); o[1] = f2bf(v.y); o[2] = f2bf(v.z); o[3] = f2bf(v.w);
    *(usvec4*)(dst + i) = o;
  }
}

// rpbm[cls][h][n][m] = rpb[relidx(n,m)][h] + pe_b[h] + mask(cls,n,m)
__global__ __launch_bounds__(256)
void rpbm_kernel(const float* __restrict__ rpb, const float* __restrict__ pe_b,
                 float* __restrict__ out) {
  int idx = blockIdx.x * 256 + threadIdx.x;          // 131072
  int m = idx & 63, n = (idx >> 6) & 63, hh = (idx >> 12) & 7, cls = idx >> 15;
  int dy = (n >> 3) - (m >> 3) + 7, dx = (n & 7) - (m & 7) + 7;
  float v = rpb[(dy * 15 + dx) * 8 + hh] + pe_b[hh];
  int lastR = cls >> 1, lastC = cls & 1;
  int rn = lastR ? (((n >> 3) < 4) ? 1 : 2) : 0;
  int cn = lastC ? (((n & 7) < 4) ? 1 : 2) : 0;
  int rm = lastR ? (((m >> 3) < 4) ? 1 : 2) : 0;
  int cm = lastC ? (((m & 7) < 4) ? 1 : 2) : 0;
  if (rn * 3 + cn != rm * 3 + cm) v -= 100.0f;
  out[idx] = v;
}

// mconv[h][n][nn] = (n==nn) + (|nn-n|<=7 ? pe_w[h][nn-n+7] : 0), bf16
__global__ __launch_bounds__(256)
void mconv_kernel(const float* __restrict__ pe_w, u16* __restrict__ out) {
  int idx = blockIdx.x * 256 + threadIdx.x;          // 32768
  int nn = idx & 63, n = (idx >> 6) & 63, hh = idx >> 12;
  int d = nn - n;
  float v = (d == 0) ? 1.0f : 0.0f;
  if (d >= -7 && d <= 7) v += pe_w[hh * 15 + d + 7];
  out[idx] = f2bf(v);
}

// ---------------------------------------------------------------------------
// GEMM v3: C[M,N] = A[M,K]bf16 * B[N,K]bf16^T. 128x128 tile, BK=32,
// double-buffered LDS, ONE barrier per K-step, global_load_lds width16,
// XCD-aware bijective block swizzle (all grids are multiples of 8).
// EPI: 0 qkv (+bias, scale q, bf16) | 1 proj (+bias, bf16 linear)
//      2 fc1 (+bias, exact gelu, bf16) | 3 fc2 (+bias + residual f32 in d_out)
// ---------------------------------------------------------------------------
template<int EPI>
__global__ __launch_bounds__(256)
void gemm3(const u16* __restrict__ A, const u16* __restrict__ Bw,
           const float* __restrict__ bias, u16* outb, float* outf,
           const float* __restrict__ extra, int N, int K, int row0)
{
  __shared__ __align__(16) u16 As[2][128 * 32];
  __shared__ __align__(16) u16 Bs[2][128 * 32];
  const int tid  = threadIdx.x;
  const int lane = tid & 63;
  const int wid  = tid >> 6;
  const int lo   = lane & 15, hi = lane >> 4;

  // XCD swizzle: nwg % 8 == 0 for all our grids -> bijective
  const int lin = blockIdx.y * gridDim.x + blockIdx.x;
  const int nwg = gridDim.x * gridDim.y;
  const int sw  = (lin & 7) * (nwg >> 3) + (lin >> 3);
  const int n0  = (sw % gridDim.x) * 128;
  const int m0  = (sw / gridDim.x) * 128;

  const int wm = (wid >> 1) * 64, wn = (wid & 1) * 64;

  floatx4 acc[4][4] = {};

  const int r0c = tid >> 2, q0 = tid & 3;
  const int r1c = (256 + tid) >> 2;

  auto issue = [&](int kt, int buf) {
    async_copy16(A  + (size_t)(m0 + r0c) * K + kt + q0 * 8, &As[buf][(size_t)tid * 8]);
    async_copy16(A  + (size_t)(m0 + r1c) * K + kt + q0 * 8, &As[buf][(size_t)(256 + tid) * 8]);
    async_copy16(Bw + (size_t)(n0 + r0c) * K + kt + q0 * 8, &Bs[buf][(size_t)tid * 8]);
    async_copy16(Bw + (size_t)(n0 + r1c) * K + kt + q0 * 8, &Bs[buf][(size_t)(256 + tid) * 8]);
  };

  issue(0, 0);
  const int nk = K >> 5;
  for (int t = 0; t < nk; ++t) {
    __syncthreads();                       // drains vmcnt -> buf[t&1] ready
    if (t + 1 < nk) issue((t + 1) << 5, (t + 1) & 1);
    const u16* as = As[t & 1];
    const u16* bs = Bs[t & 1];
    svec8 af[4], bfr[4];
    #pragma unroll
    for (int i = 0; i < 4; ++i)
      af[i] = *(const svec8*)&as[(wm + i * 16 + lo) * 32 + hi * 8];
    #pragma unroll
    for (int i = 0; i < 4; ++i)
      bfr[i] = *(const svec8*)&bs[(wn + i * 16 + lo) * 32 + hi * 8];
    #pragma unroll
    for (int mi = 0; mi < 4; ++mi)
      #pragma unroll
      for (int ni = 0; ni < 4; ++ni)
        acc[mi][ni] = __builtin_amdgcn_mfma_f32_16x16x32_bf16(af[mi], bfr[ni], acc[mi][ni], 0, 0, 0);
  }

  #pragma unroll
  for (int mi = 0; mi < 4; ++mi) {
    #pragma unroll
    for (int ni = 0; ni < 4; ++ni) {
      #pragma unroll
      for (int j = 0; j < 4; ++j) {
        int r = m0 + wm + mi * 16 + hi * 4 + j;
        int c = n0 + wn + ni * 16 + lo;
        float v = acc[mi][ni][j] + bias[c];
        if constexpr (EPI == 0) {
          if (c < 256) v *= SCALE_Q;
          outb[(size_t)r * N + c] = f2bf(v);
        } else if constexpr (EPI == 1) {
          outb[(size_t)r * N + c] = f2bf(v);
        } else if constexpr (EPI == 2) {
          float gv = 0.5f * v * (1.0f + erff(v * 0.70710678118654752f));
          outb[(size_t)r * N + c] = f2bf(gv);
        } else {
          size_t o = (size_t)(row0 + r) * N + c;
          outf[o] = extra[o] + v;
        }
      }
    }
  }
}

// ---------------------------------------------------------------------------
// Attention: one block per (window, head), 4 waves; wave wv owns queries
// [wv*16, wv*16+16). Logits = (I+T) @ S_bf16 (MFMA, acc init = rpbm which
// folds rpb + pe_b + shift mask). In-register softmax. PV via LDS.
// ---------------------------------------------------------------------------
__global__ __launch_bounds__(256)
void attn2(const u16* __restrict__ qkv, const float* __restrict__ rpbm,
           const u16* __restrict__ mconv, u16* __restrict__ outb)
{
  __shared__ __align__(16) u16 Ks[64 * 40];
  __shared__ __align__(16) u16 Vt[32 * 72];
  __shared__ __align__(16) u16 ST[64 * 72];
  __shared__ __align__(16) u16 Pm[64 * 72];

  const int tid  = threadIdx.x;
  const int lane = tid & 63, wv = tid >> 6;
  const int lo   = lane & 15, hi = lane >> 4;
  const int wId  = blockIdx.x >> 3;
  const int h    = blockIdx.x & 7;
  const int wi   = wId & 255;
  const int cls  = (((wi >> 4) == 15) ? 2 : 0) + (((wi & 15) == 15) ? 1 : 0);
  const int m0   = wv * 16;

  { // stage k and V^T
    int r = tid >> 2, ch = tid & 3;
    const size_t base = (size_t)(wId * 64 + r) * 768 + h * 32 + ch * 8;
    *(ivec4*)&Ks[r * 40 + ch * 8] = *(const ivec4*)(qkv + base + 256);
    ivec4 vv = *(const ivec4*)(qkv + base + 512);
    const u16* pv = (const u16*)&vv;
    #pragma unroll
    for (int e = 0; e < 8; ++e) Vt[(ch * 8 + e) * 72 + r] = pv[e];
  }
  __syncthreads();

  { // QK^T (K=32): A = q rows (global), B = k rows (LDS). Write S^T bf16.
    svec8 qa = *(const svec8*)(qkv + (size_t)(wId * 64 + m0 + lo) * 768 + h * 32 + hi * 8);
    floatx4 z = {0.f, 0.f, 0.f, 0.f};
    #pragma unroll
    for (int nb = 0; nb < 4; ++nb) {
      svec8 kb = *(const svec8*)&Ks[(nb * 16 + lo) * 40 + hi * 8];
      floatx4 s = __builtin_amdgcn_mfma_f32_16x16x32_bf16(qa, kb, z, 0, 0, 0);
      #pragma unroll
      for (int jp = 0; jp < 2; ++jp) {
        u32 pk = (u32)f2bf(s[jp * 2]) | ((u32)f2bf(s[jp * 2 + 1]) << 16);
        *(u32*)&ST[(nb * 16 + lo) * 72 + m0 + hi * 4 + jp * 2] = pk;
      }
    }
  }
  __syncthreads();

  floatx4 acc[4];
  { // conv-MFMA: L = (I+T) @ S, acc init = rpbm
    const float* rb = rpbm + (size_t)(cls * 8 + h) * 4096;
    #pragma unroll
    for (int nb = 0; nb < 4; ++nb)
      #pragma unroll
      for (int j = 0; j < 4; ++j)
        acc[nb][j] = rb[(m0 + hi * 4 + j) * 64 + nb * 16 + lo];
    svec8 mf0 = *(const svec8*)(mconv + ((h * 64 + m0 + lo) * 64 + hi * 8));
    svec8 mf1 = *(const svec8*)(mconv + ((h * 64 + m0 + lo) * 64 + 32 + hi * 8));
    #pragma unroll
    for (int nb = 0; nb < 4; ++nb) {
      svec8 st0 = *(const svec8*)&ST[(nb * 16 + lo) * 72 + hi * 8];
      svec8 st1 = *(const svec8*)&ST[(nb * 16 + lo) * 72 + 32 + hi * 8];
      acc[nb] = __builtin_amdgcn_mfma_f32_16x16x32_bf16(mf0, st0, acc[nb], 0, 0, 0);
      acc[nb] = __builtin_amdgcn_mfma_f32_16x16x32_bf16(mf1, st1, acc[nb], 0, 0, 0);
    }
  }

  { // in-register softmax over keys
    float ev[4][4], inv[4];
    #pragma unroll
    for (int j = 0; j < 4; ++j) {
      float m_ = fmaxf(fmaxf(acc[0][j], acc[1][j]), fmaxf(acc[2][j], acc[3][j]));
      m_ = fmaxf(m_, __shfl_xor(m_, 1)); m_ = fmaxf(m_, __shfl_xor(m_, 2));
      m_ = fmaxf(m_, __shfl_xor(m_, 4)); m_ = fmaxf(m_, __shfl_xor(m_, 8));
      #pragma unroll
      for (int nb = 0; nb < 4; ++nb) ev[nb][j] = __expf(acc[nb][j] - m_);
      float s_ = ev[0][j] + ev[1][j] + ev[2][j] + ev[3][j];
      s_ += __shfl_xor(s_, 1); s_ += __shfl_xor(s_, 2);
      s_ += __shfl_xor(s_, 4); s_ += __shfl_xor(s_, 8);
      inv[j] = __builtin_amdgcn_rcpf(s_);
    }
    #pragma unroll
    for (int nb = 0; nb < 4; ++nb)
      #pragma unroll
      for (int j = 0; j < 4; ++j)
        Pm[(m0 + hi * 4 + j) * 72 + nb * 16 + lo] = f2bf(ev[nb][j] * inv[j]);
  }
  __syncthreads();

  { // PV
    floatx4 oacc[2] = {};
    #pragma unroll
    for (int ks = 0; ks < 2; ++ks) {
      svec8 pa = *(const svec8*)&Pm[(m0 + lo) * 72 + ks * 32 + hi * 8];
      #pragma unroll
      for (int nb = 0; nb < 2; ++nb) {
        svec8 vb = *(const svec8*)&Vt[(nb * 16 + lo) * 72 + ks * 32 + hi * 8];
        oacc[nb] = __builtin_amdgcn_mfma_f32_16x16x32_bf16(pa, vb, oacc[nb], 0, 0, 0);
      }
    }
    #pragma unroll
    for (int nb = 0; nb < 2; ++nb)
      #pragma unroll
      for (int j = 0; j < 4; ++j)
        outb[(size_t)(wId * 64 + m0 + hi * 4 + j) * 256 + h * 32 + nb * 16 + lo] = f2bf(oacc[nb][j]);
  }
}

// ---------------------------------------------------------------------------
extern "C" void kernel_launch(void* const* d_in, const int* in_sizes, int n_in,
                              void* d_out, int out_size, void* d_ws, size_t ws_size,
                              hipStream_t stream)
{
  const float* x      = (const float*)d_in[0];
  const float* n1g    = (const float*)d_in[1];
  const float* n1b    = (const float*)d_in[2];
  const float* qkv_w  = (const float*)d_in[3];
  const float* qkv_b  = (const float*)d_in[4];
  const float* rpb    = (const float*)d_in[5];
  const float* pe_w   = (const float*)d_in[6];
  const float* pe_b   = (const float*)d_in[7];
  const float* proj_w = (const float*)d_in[8];
  const float* proj_b = (const float*)d_in[9];
  const float* n2g    = (const float*)d_in[10];
  const float* n2b    = (const float*)d_in[11];
  const float* fc1_w  = (const float*)d_in[12];
  const float* fc1_b  = (const float*)d_in[13];
  const float* fc2_w  = (const float*)d_in[14];
  const float* fc2_b  = (const float*)d_in[15];
  float* outf = (float*)d_out;

  char* ws = (char*)d_ws;
  u16* qkvb    = (u16*)ws;                          // [0,192M) phase1
  u16* winb    = (u16*)(ws + (192ull << 20));       // [192,256M) phase1
  u16* yb      = (u16*)ws;                          // [0,64M)   phase2
  u16* h1b     = (u16*)(ws + (64ull << 20));        // [64,192M) phase2
  u16* projoutb= (u16*)(ws + (128ull << 20));       // [128,192M) (dead before h1 use)
  u16* fc1wb   = (u16*)(ws + (192ull << 20));       // 512K (after proj reads winb)
  u16* fc2wb   = (u16*)(ws + (192ull << 20) + (1ull << 19));

  // d_out scratch (dead until resid_ln2)
  u16*   qkvwb  = (u16*)d_out;                              // 384K
  float* rpbmT  = (float*)((char*)d_out + (1ull << 19));    // 512K
  u16*   mconvT = (u16*)((char*)d_out + (1ull << 20));      // 64K
  u16*   projwb = (u16*)((char*)d_out + (1ull << 20) + (1ull << 18)); // 128K

  // setup
  cvt_kernel<<<192, 256, 0, stream>>>(qkv_w, qkvwb, 196608);
  rpbm_kernel<<<512, 256, 0, stream>>>(rpb, pe_b, rpbmT);
  mconv_kernel<<<128, 256, 0, stream>>>(pe_w, mconvT);
  cvt_kernel<<<64, 256, 0, stream>>>(proj_w, projwb, 65536);

  // 1) LN1 + shift + window partition
  ln_kernel<1><<<32768, 256, 0, stream>>>(x, n1g, n1b, winb);
  // 2) QKV GEMM
  gemm3<0><<<dim3(6, 1024), 256, 0, stream>>>(winb, qkvwb, qkv_b, qkvb, nullptr, nullptr, 768, 256, 0);
  // 3) attention -> winb (overwrites LN1 output)
  attn2<<<16384, 256, 0, stream>>>(qkvb, rpbmT, mconvT, winb);
  // 4) proj GEMM -> projout bf16 (linear, window order)
  gemm3<1><<<dim3(2, 1024), 256, 0, stream>>>(winb, projwb, proj_b, projoutb, nullptr, nullptr, 256, 256, 0);
  // 4b) convert fc weights into [192,256M) (winb now dead)
  cvt_kernel<<<256, 256, 0, stream>>>(fc1_w, fc1wb, 262144);
  cvt_kernel<<<256, 256, 0, stream>>>(fc2_w, fc2wb, 262144);
  // 5) fused unshift+residual+LN2: x2 -> d_out, yb -> ws
  resid_ln2<<<32768, 256, 0, stream>>>(x, projoutb, n2g, n2b, outf, yb);
  // 6) MLP in two M-halves (h1 = 128 MiB in [64,192M))
  for (int half = 0; half < 2; ++half) {
    int r0 = half * 65536;
    gemm3<2><<<dim3(8, 512), 256, 0, stream>>>(yb + (size_t)r0 * 256, fc1wb, fc1_b, h1b, nullptr, nullptr, 1024, 256, 0);
    gemm3<3><<<dim3(2, 512), 256, 0, stream>>>(h1b, fc2wb, fc2_b, nullptr, outf, outf, 256, 1024, r0);
  }
}

// Round 4
// 879.505 us; speedup vs baseline: 1.6328x; 1.0751x over previous
//
#include <hip/hip_runtime.h>

// ---------------------------------------------------------------------------
// Swin block on MI355X. B=8, H=W=128, C=256, NH=8, HD=32, WS=8, SS=4, N=64,
// NW=256, tokens M=131072, HID=1024.
// ws (256 MiB):
//   phase1: qkvb [0,192M) | winb [192,256M)
//   phase2 (post-attn): yb [0,64M) | h1b [64,192M) | projout [128,192M) (dead
//           before h1b written) | fc1wb/fc2wb [192,256M) (after proj reads winb)
// d_out doubles as scratch until resid_ln2: qkvwb [0,384K), rpbm [512K,1M),
//   mconv [1M,1M+64K), projwb [1.25M,+128K)
// ---------------------------------------------------------------------------

typedef unsigned short u16;
typedef unsigned int   u32;
typedef __attribute__((ext_vector_type(4))) int   ivec4;
typedef __attribute__((ext_vector_type(4))) float fvec4;
typedef __attribute__((ext_vector_type(8))) short svec8;
typedef __attribute__((ext_vector_type(4))) unsigned short usvec4;
typedef __attribute__((ext_vector_type(4))) float floatx4;

#define SCALE_Q 0.17677669529663687f

__device__ __forceinline__ u16 f2bf(float f) {
  union { float f; u32 u; } v; v.f = f;
  u32 r = v.u + 0x7FFFu + ((v.u >> 16) & 1u);
  return (u16)(r >> 16);
}
__device__ __forceinline__ float bf2f(u16 h) {
  union { u32 u; float f; } v; v.u = ((u32)h) << 16; return v.f;
}

__device__ __forceinline__ void async_copy16(const u16* g, u16* l) {
  __builtin_amdgcn_global_load_lds(
      (const __attribute__((address_space(1))) u32*)g,
      (__attribute__((address_space(3))) u32*)l, 16, 0, 0);
}

// ---------------------------------------------------------------------------
// LN1: wave per token (4 tokens/block), float4/lane, shuffle-only reduce.
// SHIFT=1: token order = shifted window partition (gather read of x).
// ---------------------------------------------------------------------------
template<int SHIFT>
__global__ __launch_bounds__(256)
void ln_kernel(const float* __restrict__ x, const float* __restrict__ g,
               const float* __restrict__ b, u16* __restrict__ out)
{
  const int t    = blockIdx.x * 4 + (threadIdx.x >> 6);
  const int lane = threadIdx.x & 63;
  const int c    = lane * 4;
  size_t src;
  if constexpr (SHIFT) {
    int w  = t >> 6, tk = t & 63;
    int bi = w >> 8, wi = w & 255;
    int hr = ((wi >> 4) << 3) + (tk >> 3);
    int wr = ((wi & 15) << 3) + (tk & 7);
    int ho = (hr + 4) & 127, wo = (wr + 4) & 127;
    src = ((size_t)bi * 16384 + (size_t)ho * 128 + wo) * 256 + c;
  } else {
    src = (size_t)t * 256 + c;
  }
  fvec4 v = *(const fvec4*)(x + src);
  float s  = v.x + v.y + v.z + v.w;
  float s2 = v.x * v.x + v.y * v.y + v.z * v.z + v.w * v.w;
  #pragma unroll
  for (int o = 32; o > 0; o >>= 1) { s += __shfl_xor(s, o); s2 += __shfl_xor(s2, o); }
  float mu  = s * (1.0f / 256.0f);
  float var = s2 * (1.0f / 256.0f) - mu * mu;
  float inv = rsqrtf(var + 1e-5f);
  fvec4 gg = *(const fvec4*)(g + c);
  fvec4 bb = *(const fvec4*)(b + c);
  usvec4 o4;
  o4[0] = f2bf((v.x - mu) * inv * gg.x + bb.x);
  o4[1] = f2bf((v.y - mu) * inv * gg.y + bb.y);
  o4[2] = f2bf((v.z - mu) * inv * gg.z + bb.z);
  o4[3] = f2bf((v.w - mu) * inv * gg.w + bb.w);
  *(usvec4*)(out + (size_t)t * 256 + c) = o4;
}

// ---------------------------------------------------------------------------
// resid_ln2: wave per pixel P (row-major). x2 = x + permute(proj_out);
// write x2 (f32, d_out) and LN2(x2) (bf16, yb).
// ---------------------------------------------------------------------------
__global__ __launch_bounds__(256)
void resid_ln2(const float* __restrict__ x, const u16* __restrict__ projout,
               const float* __restrict__ g, const float* __restrict__ b,
               float* __restrict__ x2, u16* __restrict__ yb)
{
  const int P    = blockIdx.x * 4 + (threadIdx.x >> 6);
  const int lane = threadIdx.x & 63;
  const int c    = lane * 4;
  const int bi = P >> 14, ho = (P >> 7) & 127, wo = P & 127;
  const int hr = (ho + 124) & 127, wr = (wo + 124) & 127;
  const int token = (((bi << 8) + ((hr >> 3) << 4) + (wr >> 3)) << 6)
                    + ((hr & 7) << 3) + (wr & 7);
  fvec4 xv = *(const fvec4*)(x + (size_t)P * 256 + c);
  usvec4 pv = *(const usvec4*)(projout + (size_t)token * 256 + c);
  fvec4 v;
  v.x = xv.x + bf2f(pv[0]); v.y = xv.y + bf2f(pv[1]);
  v.z = xv.z + bf2f(pv[2]); v.w = xv.w + bf2f(pv[3]);
  *(fvec4*)(x2 + (size_t)P * 256 + c) = v;
  float s  = v.x + v.y + v.z + v.w;
  float s2 = v.x * v.x + v.y * v.y + v.z * v.z + v.w * v.w;
  #pragma unroll
  for (int o = 32; o > 0; o >>= 1) { s += __shfl_xor(s, o); s2 += __shfl_xor(s2, o); }
  float mu  = s * (1.0f / 256.0f);
  float var = s2 * (1.0f / 256.0f) - mu * mu;
  float inv = rsqrtf(var + 1e-5f);
  fvec4 gg = *(const fvec4*)(g + c);
  fvec4 bb = *(const fvec4*)(b + c);
  usvec4 o4;
  o4[0] = f2bf((v.x - mu) * inv * gg.x + bb.x);
  o4[1] = f2bf((v.y - mu) * inv * gg.y + bb.y);
  o4[2] = f2bf((v.z - mu) * inv * gg.z + bb.z);
  o4[3] = f2bf((v.w - mu) * inv * gg.w + bb.w);
  *(usvec4*)(yb + (size_t)P * 256 + c) = o4;
}

// ---------------------------------------------------------------------------
// Small setup kernels
// ---------------------------------------------------------------------------
__global__ __launch_bounds__(256)
void cvt_kernel(const float* __restrict__ src, u16* __restrict__ dst, int n) {
  int i = (blockIdx.x * 256 + threadIdx.x) * 4;
  if (i < n) {
    fvec4 v = *(const fvec4*)(src + i);
    usvec4 o; o[0] = f2bf(v.x); o[1] = f2bf(v.y); o[2] = f2bf(v.z); o[3] = f2bf(v.w);
    *(usvec4*)(dst + i) = o;
  }
}

// rpbm[cls][h][n][m] = rpb[relidx(n,m)][h] + pe_b[h] + mask(cls,n,m)
__global__ __launch_bounds__(256)
void rpbm_kernel(const float* __restrict__ rpb, const float* __restrict__ pe_b,
                 float* __restrict__ out) {
  int idx = blockIdx.x * 256 + threadIdx.x;          // 131072
  int m = idx & 63, n = (idx >> 6) & 63, hh = (idx >> 12) & 7, cls = idx >> 15;
  int dy = (n >> 3) - (m >> 3) + 7, dx = (n & 7) - (m & 7) + 7;
  float v = rpb[(dy * 15 + dx) * 8 + hh] + pe_b[hh];
  int lastR = cls >> 1, lastC = cls & 1;
  int rn = lastR ? (((n >> 3) < 4) ? 1 : 2) : 0;
  int cn = lastC ? (((n & 7) < 4) ? 1 : 2) : 0;
  int rm = lastR ? (((m >> 3) < 4) ? 1 : 2) : 0;
  int cm = lastC ? (((m & 7) < 4) ? 1 : 2) : 0;
  if (rn * 3 + cn != rm * 3 + cm) v -= 100.0f;
  out[idx] = v;
}

// mconv[h][n][nn] = (n==nn) + (|nn-n|<=7 ? pe_w[h][nn-n+7] : 0), bf16
__global__ __launch_bounds__(256)
void mconv_kernel(const float* __restrict__ pe_w, u16* __restrict__ out) {
  int idx = blockIdx.x * 256 + threadIdx.x;          // 32768
  int nn = idx & 63, n = (idx >> 6) & 63, hh = idx >> 12;
  int d = nn - n;
  float v = (d == 0) ? 1.0f : 0.0f;
  if (d >= -7 && d <= 7) v += pe_w[hh * 15 + d + 7];
  out[idx] = f2bf(v);
}

// ---------------------------------------------------------------------------
// GEMM v4: C[M,N] = A[M,K]bf16 * B[N,K]bf16^T. 128x128 tile, BK=32,
// *** 8 waves (512 thr), wave tile 32x64, acc = 2x4 frags (32 AGPR) ***
// -> total regs <=128 -> 4 waves/SIMD -> 2 blocks/CU resident (vs ~1.85 at
//    the 4-wave/64-AGPR partition). Double-buffered LDS, one barrier/K-step,
//    global_load_lds width16, XCD-aware bijective swizzle (grids % 8 == 0).
// EPI: 0 qkv (+bias, scale q, bf16) | 1 proj (+bias, bf16 linear)
//      2 fc1 (+bias, exact gelu, bf16) | 3 fc2 (+bias + residual f32 in d_out)
// ---------------------------------------------------------------------------
template<int EPI>
__global__ __launch_bounds__(512, 4)
void gemm4(const u16* __restrict__ A, const u16* __restrict__ Bw,
           const float* __restrict__ bias, u16* outb, float* outf,
           const float* __restrict__ extra, int N, int K, int row0)
{
  __shared__ __align__(16) u16 As[2][128 * 32];
  __shared__ __align__(16) u16 Bs[2][128 * 32];
  const int tid  = threadIdx.x;
  const int lane = tid & 63;
  const int wid  = tid >> 6;            // 0..7
  const int lo   = lane & 15, hi = lane >> 4;

  // XCD swizzle: nwg % 8 == 0 for all our grids -> bijective
  const int lin = blockIdx.y * gridDim.x + blockIdx.x;
  const int nwg = gridDim.x * gridDim.y;
  const int sw  = (lin & 7) * (nwg >> 3) + (lin >> 3);
  const int n0  = (sw % gridDim.x) * 128;
  const int m0  = (sw / gridDim.x) * 128;

  const int wm = (wid >> 1) * 32;       // 0,32,64,96
  const int wn = (wid & 1) * 64;        // 0,64

  floatx4 acc[2][4] = {};

  const int rr = tid >> 2, qq = tid & 3;   // 512 thr: rows 0..127, 4 chunks

  auto issue = [&](int kt, int buf) {
    async_copy16(A  + (size_t)(m0 + rr) * K + kt + qq * 8, &As[buf][(size_t)tid * 8]);
    async_copy16(Bw + (size_t)(n0 + rr) * K + kt + qq * 8, &Bs[buf][(size_t)tid * 8]);
  };

  issue(0, 0);
  const int nk = K >> 5;
  for (int t = 0; t < nk; ++t) {
    __syncthreads();                       // buf[t&1] landed (vmcnt drained)
    if (t + 1 < nk) issue((t + 1) << 5, (t + 1) & 1);
    const u16* as = As[t & 1];
    const u16* bs = Bs[t & 1];
    svec8 af[2], bfr[4];
    #pragma unroll
    for (int i = 0; i < 2; ++i)
      af[i] = *(const svec8*)&as[(wm + i * 16 + lo) * 32 + hi * 8];
    #pragma unroll
    for (int i = 0; i < 4; ++i)
      bfr[i] = *(const svec8*)&bs[(wn + i * 16 + lo) * 32 + hi * 8];
    #pragma unroll
    for (int mi = 0; mi < 2; ++mi)
      #pragma unroll
      for (int ni = 0; ni < 4; ++ni)
        acc[mi][ni] = __builtin_amdgcn_mfma_f32_16x16x32_bf16(af[mi], bfr[ni], acc[mi][ni], 0, 0, 0);
  }

  #pragma unroll
  for (int mi = 0; mi < 2; ++mi) {
    #pragma unroll
    for (int ni = 0; ni < 4; ++ni) {
      #pragma unroll
      for (int j = 0; j < 4; ++j) {
        int r = m0 + wm + mi * 16 + hi * 4 + j;
        int c = n0 + wn + ni * 16 + lo;
        float v = acc[mi][ni][j] + bias[c];
        if constexpr (EPI == 0) {
          if (c < 256) v *= SCALE_Q;
          outb[(size_t)r * N + c] = f2bf(v);
        } else if constexpr (EPI == 1) {
          outb[(size_t)r * N + c] = f2bf(v);
        } else if constexpr (EPI == 2) {
          float gv = 0.5f * v * (1.0f + erff(v * 0.70710678118654752f));
          outb[(size_t)r * N + c] = f2bf(gv);
        } else {
          size_t o = (size_t)(row0 + r) * N + c;
          outf[o] = extra[o] + v;
        }
      }
    }
  }
}

// ---------------------------------------------------------------------------
// Attention: one block per (window, head), 4 waves; wave wv owns queries
// [wv*16, wv*16+16). Logits = (I+T) @ S_bf16 (MFMA, acc init = rpbm which
// folds rpb + pe_b + shift mask). In-register softmax. PV via LDS.
// ---------------------------------------------------------------------------
__global__ __launch_bounds__(256)
void attn2(const u16* __restrict__ qkv, const float* __restrict__ rpbm,
           const u16* __restrict__ mconv, u16* __restrict__ outb)
{
  __shared__ __align__(16) u16 Ks[64 * 40];
  __shared__ __align__(16) u16 Vt[32 * 72];
  __shared__ __align__(16) u16 ST[64 * 72];
  __shared__ __align__(16) u16 Pm[64 * 72];

  const int tid  = threadIdx.x;
  const int lane = tid & 63, wv = tid >> 6;
  const int lo   = lane & 15, hi = lane >> 4;
  const int wId  = blockIdx.x >> 3;
  const int h    = blockIdx.x & 7;
  const int wi   = wId & 255;
  const int cls  = (((wi >> 4) == 15) ? 2 : 0) + (((wi & 15) == 15) ? 1 : 0);
  const int m0   = wv * 16;

  { // stage k and V^T
    int r = tid >> 2, ch = tid & 3;
    const size_t base = (size_t)(wId * 64 + r) * 768 + h * 32 + ch * 8;
    *(ivec4*)&Ks[r * 40 + ch * 8] = *(const ivec4*)(qkv + base + 256);
    ivec4 vv = *(const ivec4*)(qkv + base + 512);
    const u16* pv = (const u16*)&vv;
    #pragma unroll
    for (int e = 0; e < 8; ++e) Vt[(ch * 8 + e) * 72 + r] = pv[e];
  }
  __syncthreads();

  { // QK^T (K=32): A = q rows (global), B = k rows (LDS). Write S^T bf16.
    svec8 qa = *(const svec8*)(qkv + (size_t)(wId * 64 + m0 + lo) * 768 + h * 32 + hi * 8);
    floatx4 z = {0.f, 0.f, 0.f, 0.f};
    #pragma unroll
    for (int nb = 0; nb < 4; ++nb) {
      svec8 kb = *(const svec8*)&Ks[(nb * 16 + lo) * 40 + hi * 8];
      floatx4 s = __builtin_amdgcn_mfma_f32_16x16x32_bf16(qa, kb, z, 0, 0, 0);
      #pragma unroll
      for (int jp = 0; jp < 2; ++jp) {
        u32 pk = (u32)f2bf(s[jp * 2]) | ((u32)f2bf(s[jp * 2 + 1]) << 16);
        *(u32*)&ST[(nb * 16 + lo) * 72 + m0 + hi * 4 + jp * 2] = pk;
      }
    }
  }
  __syncthreads();

  floatx4 acc[4];
  { // conv-MFMA: L = (I+T) @ S, acc init = rpbm
    const float* rb = rpbm + (size_t)(cls * 8 + h) * 4096;
    #pragma unroll
    for (int nb = 0; nb < 4; ++nb)
      #pragma unroll
      for (int j = 0; j < 4; ++j)
        acc[nb][j] = rb[(m0 + hi * 4 + j) * 64 + nb * 16 + lo];
    svec8 mf0 = *(const svec8*)(mconv + ((h * 64 + m0 + lo) * 64 + hi * 8));
    svec8 mf1 = *(const svec8*)(mconv + ((h * 64 + m0 + lo) * 64 + 32 + hi * 8));
    #pragma unroll
    for (int nb = 0; nb < 4; ++nb) {
      svec8 st0 = *(const svec8*)&ST[(nb * 16 + lo) * 72 + hi * 8];
      svec8 st1 = *(const svec8*)&ST[(nb * 16 + lo) * 72 + 32 + hi * 8];
      acc[nb] = __builtin_amdgcn_mfma_f32_16x16x32_bf16(mf0, st0, acc[nb], 0, 0, 0);
      acc[nb] = __builtin_amdgcn_mfma_f32_16x16x32_bf16(mf1, st1, acc[nb], 0, 0, 0);
    }
  }

  { // in-register softmax over keys
    float ev[4][4], inv[4];
    #pragma unroll
    for (int j = 0; j < 4; ++j) {
      float m_ = fmaxf(fmaxf(acc[0][j], acc[1][j]), fmaxf(acc[2][j], acc[3][j]));
      m_ = fmaxf(m_, __shfl_xor(m_, 1)); m_ = fmaxf(m_, __shfl_xor(m_, 2));
      m_ = fmaxf(m_, __shfl_xor(m_, 4)); m_ = fmaxf(m_, __shfl_xor(m_, 8));
      #pragma unroll
      for (int nb = 0; nb < 4; ++nb) ev[nb][j] = __expf(acc[nb][j] - m_);
      float s_ = ev[0][j] + ev[1][j] + ev[2][j] + ev[3][j];
      s_ += __shfl_xor(s_, 1); s_ += __shfl_xor(s_, 2);
      s_ += __shfl_xor(s_, 4); s_ += __shfl_xor(s_, 8);
      inv[j] = __builtin_amdgcn_rcpf(s_);
    }
    #pragma unroll
    for (int nb = 0; nb < 4; ++nb)
      #pragma unroll
      for (int j = 0; j < 4; ++j)
        Pm[(m0 + hi * 4 + j) * 72 + nb * 16 + lo] = f2bf(ev[nb][j] * inv[j]);
  }
  __syncthreads();

  { // PV
    floatx4 oacc[2] = {};
    #pragma unroll
    for (int ks = 0; ks < 2; ++ks) {
      svec8 pa = *(const svec8*)&Pm[(m0 + lo) * 72 + ks * 32 + hi * 8];
      #pragma unroll
      for (int nb = 0; nb < 2; ++nb) {
        svec8 vb = *(const svec8*)&Vt[(nb * 16 + lo) * 72 + ks * 32 + hi * 8];
        oacc[nb] = __builtin_amdgcn_mfma_f32_16x16x32_bf16(pa, vb, oacc[nb], 0, 0, 0);
      }
    }
    #pragma unroll
    for (int nb = 0; nb < 2; ++nb)
      #pragma unroll
      for (int j = 0; j < 4; ++j)
        outb[(size_t)(wId * 64 + m0 + hi * 4 + j) * 256 + h * 32 + nb * 16 + lo] = f2bf(oacc[nb][j]);
  }
}

// ---------------------------------------------------------------------------
extern "C" void kernel_launch(void* const* d_in, const int* in_sizes, int n_in,
                              void* d_out, int out_size, void* d_ws, size_t ws_size,
                              hipStream_t stream)
{
  const float* x      = (const float*)d_in[0];
  const float* n1g    = (const float*)d_in[1];
  const float* n1b    = (const float*)d_in[2];
  const float* qkv_w  = (const float*)d_in[3];
  const float* qkv_b  = (const float*)d_in[4];
  const float* rpb    = (const float*)d_in[5];
  const float* pe_w   = (const float*)d_in[6];
  const float* pe_b   = (const float*)d_in[7];
  const float* proj_w = (const float*)d_in[8];
  const float* proj_b = (const float*)d_in[9];
  const float* n2g    = (const float*)d_in[10];
  const float* n2b    = (const float*)d_in[11];
  const float* fc1_w  = (const float*)d_in[12];
  const float* fc1_b  = (const float*)d_in[13];
  const float* fc2_w  = (const float*)d_in[14];
  const float* fc2_b  = (const float*)d_in[15];
  float* outf = (float*)d_out;

  char* ws = (char*)d_ws;
  u16* qkvb    = (u16*)ws;                          // [0,192M) phase1
  u16* winb    = (u16*)(ws + (192ull << 20));       // [192,256M) phase1
  u16* yb      = (u16*)ws;                          // [0,64M)   phase2
  u16* h1b     = (u16*)(ws + (64ull << 20));        // [64,192M) phase2
  u16* projoutb= (u16*)(ws + (128ull << 20));       // [128,192M) (dead before h1 use)
  u16* fc1wb   = (u16*)(ws + (192ull << 20));       // 512K (after proj reads winb)
  u16* fc2wb   = (u16*)(ws + (192ull << 20) + (1ull << 19));

  // d_out scratch (dead until resid_ln2)
  u16*   qkvwb  = (u16*)d_out;                              // 384K
  float* rpbmT  = (float*)((char*)d_out + (1ull << 19));    // 512K
  u16*   mconvT = (u16*)((char*)d_out + (1ull << 20));      // 64K
  u16*   projwb = (u16*)((char*)d_out + (1ull << 20) + (1ull << 18)); // 128K

  // setup
  cvt_kernel<<<192, 256, 0, stream>>>(qkv_w, qkvwb, 196608);
  rpbm_kernel<<<512, 256, 0, stream>>>(rpb, pe_b, rpbmT);
  mconv_kernel<<<128, 256, 0, stream>>>(pe_w, mconvT);
  cvt_kernel<<<64, 256, 0, stream>>>(proj_w, projwb, 65536);

  // 1) LN1 + shift + window partition
  ln_kernel<1><<<32768, 256, 0, stream>>>(x, n1g, n1b, winb);
  // 2) QKV GEMM
  gemm4<0><<<dim3(6, 1024), 512, 0, stream>>>(winb, qkvwb, qkv_b, qkvb, nullptr, nullptr, 768, 256, 0);
  // 3) attention -> winb (overwrites LN1 output)
  attn2<<<16384, 256, 0, stream>>>(qkvb, rpbmT, mconvT, winb);
  // 4) proj GEMM -> projout bf16 (linear, window order)
  gemm4<1><<<dim3(2, 1024), 512, 0, stream>>>(winb, projwb, proj_b, projoutb, nullptr, nullptr, 256, 256, 0);
  // 4b) convert fc weights into [192,256M) (winb now dead)
  cvt_kernel<<<256, 256, 0, stream>>>(fc1_w, fc1wb, 262144);
  cvt_kernel<<<256, 256, 0, stream>>>(fc2_w, fc2wb, 262144);
  // 5) fused unshift+residual+LN2: x2 -> d_out, yb -> ws
  resid_ln2<<<32768, 256, 0, stream>>>(x, projoutb, n2g, n2b, outf, yb);
  // 6) MLP in two M-halves (h1 = 128 MiB in [64,192M))
  for (int half = 0; half < 2; ++half) {
    int r0 = half * 65536;
    gemm4<2><<<dim3(8, 512), 512, 0, stream>>>(yb + (size_t)r0 * 256, fc1wb, fc1_b, h1b, nullptr, nullptr, 1024, 256, 0);
    gemm4<3><<<dim3(2, 512), 512, 0, stream>>>(h1b, fc2wb, fc2_b, nullptr, outf, outf, 256, 1024, r0);
  }
}